// Round 10
// baseline (87.524 us; speedup 1.0000x reference)
//
#include <hip/hip_runtime.h>
#include <math.h>

#define BATCH 64
#define HI 224
#define WI 224
#define P1H 109
#define P1W 109
#define P2H 52
#define P2W 52
#define NPIX (HI*WI)                  // 50176 = 49 * 1024

typedef _Float16 f16;
typedef _Float16 f16x4 __attribute__((ext_vector_type(4)));
typedef _Float16 f16x8 __attribute__((ext_vector_type(8)));
typedef float    f32x4 __attribute__((ext_vector_type(4)));

#define MFMA16F(a,b,c) __builtin_amdgcn_mfma_f32_16x16x32_f16((a),(b),(c),0,0,0)

// ---------------------------------------------------------------------------
// conv1 7x7x3->8 + bias + relu + maxpool2.  MFMA 16x16x32 f16 (fp32 acc).
// kh-PAIR PACKING (R7): B variant v = [w(kh=v) n<8 | w(kh=v-1) n>=8]; vertical
// maxpool = shfl_xor(8)+max.  NEW (R10): outputs staged in the DEAD sh_b LDS
// region (bv lives in registers during the tile loop) and stored as coalesced
// 16B ulong2 -- fixes the 2x write amplification of scattered 2B f16 stores.
#define PROWS 4
#define NROWG 28                      // ceil(109/4)
#define SROWS 14
#define ROWSH 896                     // f16 per staged row (224 cols * 4)
#define STOT  (SROWS*ROWSH)           // 12544
#define SPAD  12576                   // +32 zero elems for tile-13 overrun
#define NBVAR 8
__global__ __launch_bounds__(256) void conv1_kernel(
    const float* __restrict__ x, const float* __restrict__ w1,
    const float* __restrict__ b1,
    f16* __restrict__ p1)
{
    __shared__ f16 smem[SPAD + NBVAR*16*32];   // 33344 B
    f16* sh_a   = smem;
    f16* sh_b   = smem + SPAD;                 // [8 variant][16 n][32 k]
    f16* sh_out = smem + SPAD;                 // reused: [4 pr][109 pc][8 ch]

    const int tid  = threadIdx.x;
    const int lane = tid & 63;
    const int wave = tid >> 6;
    const int bph  = blockIdx.x;
    const int b    = blockIdx.y;
    const int ph0  = PROWS*bph;
    const int ir0  = 2*ph0;

    for (int i = tid; i < NBVAR*16*32; i += 256) sh_b[i] = (f16)0.f;
    __syncthreads();

    for (int i = tid; i < 1176; i += 256) {
        const float v = w1[i];
        const int co = i & 7;
        const int t3 = i >> 3;
        const int ci = t3 % 3;
        const int kk = t3 / 3;
        const int kh = kk / 7;
        const int kw = kk - kh*7;
        const f16 val = (f16)v;
        sh_b[(kh*16     + co  )*32 + kw*4 + ci] = val;
        sh_b[((kh+1)*16 + co+8)*32 + kw*4 + ci] = val;
    }

    for (int u = wave; u < 25; u += 4) {
        const int q = u*512 + lane*8;
        if (q >= SPAD) continue;
        const int row  = q / ROWSH;
        const int rem  = q - row*ROWSH;
        const int col0 = rem >> 2;
        const int ira  = ir0 + row;
        float f0=0.f,f1=0.f,f2=0.f,f3=0.f,f4=0.f,f5=0.f;
        if (q < STOT && ira < HI) {
            const float* src = x + ((size_t)(b*HI + ira)*WI + col0)*3;
            const float2 a = *(const float2*)(src);
            const float2 c = *(const float2*)(src+2);
            const float2 e = *(const float2*)(src+4);
            f0=a.x; f1=a.y; f2=c.x; f3=c.y; f4=e.x; f5=e.y;
        }
        f16x8 hv;
        hv[0]=(f16)f0; hv[1]=(f16)f1; hv[2]=(f16)f2; hv[3]=(f16)0.f;
        hv[4]=(f16)f3; hv[5]=(f16)f4; hv[6]=(f16)f5; hv[7]=(f16)0.f;
        *(f16x8*)(sh_a + q) = hv;
    }
    __syncthreads();

    const int n16 = lane & 15;
    const int g   = lane >> 4;

    f16x8 bv[NBVAR];
#pragma unroll
    for (int v = 0; v < NBVAR; ++v)
        bv[v] = *(const f16x8*)(sh_b + (v*16 + n16)*32 + g*8);
    const float bias = b1[n16 & 7];
    __syncthreads();                  // all bv reads done; sh_b now reusable

    for (int t = wave; t < 14; t += 4) {
        const int abase = (t*16 + n16)*4 + g*8;
        f32x4 acc[4];
#pragma unroll
        for (int q = 0; q < 4; ++q) acc[q] = (f32x4){0.f,0.f,0.f,0.f};

#pragma unroll
        for (int ir = 0; ir < SROWS; ++ir) {
            const int sb = ir*ROWSH + abase;
            const f16x4 h0 = *(const f16x4*)(sh_a + sb);
            const f16x4 h1 = *(const f16x4*)(sh_a + sb + 4);
            const f16x8 ah = __builtin_shufflevector(h0,h1,0,1,2,3,4,5,6,7);
#pragma unroll
            for (int q = 0; q < 4; ++q) {
                const int v = ir - 2*q;
                if (v >= 0 && v < NBVAR)
                    acc[q] = MFMA16F(ah, bv[v], acc[q]);
            }
        }

#pragma unroll
        for (int pr = 0; pr < PROWS; ++pr) {
            const float h0 = fmaxf(acc[pr][0], acc[pr][1]);
            const float h1 = fmaxf(acc[pr][2], acc[pr][3]);
            const float v0 = fmaxf(h0, __shfl_xor(h0, 8));
            const float v1 = fmaxf(h1, __shfl_xor(h1, 8));
            if (n16 < 8) {
                const int pc0 = t*8 + 2*g;
                if (pc0 < P1W)
                    sh_out[(pr*P1W + pc0)*8 + n16] = (f16)fmaxf(v0 + bias, 0.f);
                if (pc0+1 < P1W)
                    sh_out[(pr*P1W + pc0+1)*8 + n16] = (f16)fmaxf(v1 + bias, 0.f);
            }
        }
    }
    __syncthreads();

    // coalesced output: 436 chunks of 8 f16 (16B)
    for (int c = tid; c < PROWS*P1W; c += 256) {
        const int pr = c / P1W;
        const int pc = c - pr*P1W;
        const int ph = ph0 + pr;
        if (ph < P1H)
            *(ulong2*)(p1 + ((size_t)(b*P1H + ph)*P1W + pc)*8) =
                *(const ulong2*)(sh_out + c*8);
    }
}

// ---------------------------------------------------------------------------
// conv2 5x5x8->10 + bias + relu + maxpool2, MFMA f16 single-pass.
// R10: output staged in LDS, stored as coalesced float4.
#define C2A 6144
__global__ __launch_bounds__(256) void conv2_kernel(
    const f16* __restrict__ p1,
    const float* __restrict__ w2, const float* __restrict__ b2,
    float* __restrict__ p2)
{
    __shared__ f16 smem[C2A + 16*224];       // 19456 B
    __shared__ float4 sh_o4[130];            // 520 floats, 2080 B
    f16* sh_a = smem;
    f16* sh_b = smem + C2A;
    float* sh_o = (float*)sh_o4;

    const int tid = threadIdx.x;
    const int ph  = blockIdx.x;
    const int b   = blockIdx.y;

    for (int i = tid; i < 16*224; i += 256) sh_b[i] = (f16)0.f;
    for (int i = tid; i < C2A - 5232; i += 256) sh_a[5232 + i] = (f16)0.f;
    __syncthreads();

    for (int i = tid; i < 2000; i += 256) {
        const float v = w2[i];
        const int kh = i / 400;
        int rem = i - kh*400;
        const int kw = rem / 80;
        rem -= kw*80;
        const int ci = rem / 10;
        const int co = rem - ci*10;
        sh_b[co*224 + kh*40 + kw*8 + ci] = (f16)v;
    }

    const size_t gbase = ((size_t)b*P1H + 2*ph) * (P1W*8);
    const ulong2* gsrc = (const ulong2*)(p1 + gbase);
    ulong2* gdst = (ulong2*)sh_a;
    for (int c = tid; c < 654; c += 256) gdst[c] = gsrc[c];
    __syncthreads();

    const int lane = tid & 63;
    const int wave = tid >> 6;
    const int n16  = lane & 15;
    const int g    = lane >> 4;

    f16x8 bh[7];
#pragma unroll
    for (int j = 0; j < 7; ++j)
        bh[j] = *(const f16x8*)(sh_b + n16*224 + j*32 + g*8);
    const float bias = (n16 < 10) ? b2[n16] : 0.f;

    int koff[7];
#pragma unroll
    for (int j = 0; j < 7; ++j) {
        const int chunk = 4*j + g;
        const int kh = chunk / 5;
        const int kw = chunk - kh*5;
        koff[j] = kh*872 + kw*8;
    }

    for (int t = wave; t < 7; t += 4) {
        const int c0 = t*16;
        const int pbase = (c0 + n16)*8;
        float res[2][4];
#pragma unroll
        for (int ro = 0; ro < 2; ++ro) {
            f32x4 accA = {0.f,0.f,0.f,0.f};
            f32x4 accB = {0.f,0.f,0.f,0.f};
            const int rb = ro*872 + pbase;
#pragma unroll
            for (int j = 0; j < 7; ++j) {
                const int si = rb + koff[j];
                const f16x8 ah = *(const f16x8*)(sh_a + si);
                if (j & 1) accB = MFMA16F(ah, bh[j], accB);
                else       accA = MFMA16F(ah, bh[j], accA);
            }
#pragma unroll
            for (int r = 0; r < 4; ++r) res[ro][r] = accA[r] + accB[r];
        }
        if (n16 < 10) {
#pragma unroll
            for (int q = 0; q < 2; ++q) {
                const int pc = (c0 >> 1) + 2*g + q;
                if (pc < P2W) {
                    float m = fmaxf(fmaxf(res[0][2*q], res[0][2*q+1]),
                                    fmaxf(res[1][2*q], res[1][2*q+1]));
                    sh_o[pc*10 + n16] = fmaxf(m + bias, 0.f);
                }
            }
        }
    }
    __syncthreads();

    float4* dst = (float4*)(p2 + (size_t)(b*P2H + ph)*520);
    for (int i = tid; i < 130; i += 256) dst[i] = sh_o4[i];
}

// ---------------------------------------------------------------------------
// FC stage A: partial[b][s][6], 16 K-slices of 1690 -> 1024 blocks.
#define FCSL 16
#define FCCH 1690
__global__ __launch_bounds__(256) void fcA_kernel(
    const float* __restrict__ p2, const float* __restrict__ fw,
    float* __restrict__ partial)
{
    const int s = blockIdx.x;
    const int b = blockIdx.y;
    const int base = s * FCCH;
    const float* f = p2 + (size_t)b*27040;
    float acc[6] = {0.f,0.f,0.f,0.f,0.f,0.f};
    for (int i = threadIdx.x; i < FCCH; i += 256) {
        const float v = f[base + i];
        const float* wp = fw + (size_t)(base + i)*6;
#pragma unroll
        for (int k = 0; k < 6; ++k) acc[k] = fmaf(v, wp[k], acc[k]);
    }
    __shared__ float red[4][6];
#pragma unroll
    for (int k = 0; k < 6; ++k) {
        float v = acc[k];
        for (int off = 32; off > 0; off >>= 1) v += __shfl_down(v, off);
        if ((threadIdx.x & 63) == 0) red[threadIdx.x >> 6][k] = v;
    }
    __syncthreads();
    if (threadIdx.x < 6) {
        const int k = threadIdx.x;
        partial[(b*FCSL + s)*6 + k] = red[0][k] + red[1][k] + red[2][k] + red[3][k];
    }
}

__global__ __launch_bounds__(384) void fcB_kernel(
    const float* __restrict__ partial, const float* __restrict__ fb,
    float* __restrict__ theta)
{
    const int t = threadIdx.x;                 // 384 = 64*6
    const int b = t / 6, k = t - b*6;
    float s = fb[k];
#pragma unroll
    for (int j = 0; j < FCSL; ++j) s += partial[(b*FCSL + j)*6 + k];
    theta[b*6 + k] = s;
}

// ---------------------------------------------------------------------------
// resample: 4 pixels/thread, 3 x float4 coalesced stores per thread.
__global__ __launch_bounds__(256) void resample_kernel(
    const float* __restrict__ x, const float* __restrict__ theta,
    float* __restrict__ out)
{
    const int u   = blockIdx.x;               // 64*49 blocks
    const int b   = u / 49;
    const int blk = u - b*49;
    const int pix0 = blk*1024 + threadIdx.x*4;

    const float* t = theta + b*6;
    const float a0 = t[0], a1 = t[1], a2 = t[2], a3 = t[3], a4 = t[4], a5 = t[5];
    const float* img = x + (size_t)b * (NPIX*3);

    float o[12];
#pragma unroll
    for (int p = 0; p < 4; ++p) {
        const int pix = pix0 + p;
        const int yo  = pix / WI;
        const int xo  = pix - yo * WI;

        const float fx = (float)xo, fy = (float)yo;
        const float xq = a0*fx + a1*fy + a2;
        const float yq = a3*fx + a4*fy + a5;
        const float x0f = floorf(xq), y0f = floorf(yq);
        const float dx = xq - x0f, dy = yq - y0f;
        const int x0 = (int)x0f, y0 = (int)y0f;

        const int x1 = x0 + 1, y1 = y0 + 1;
        const bool vx0 = (x0 >= 0) && (x0 <= WI-1);
        const bool vx1 = (x1 >= 0) && (x1 <= WI-1);
        const bool vy0 = (y0 >= 0) && (y0 <= HI-1);
        const bool vy1 = (y1 >= 0) && (y1 <= HI-1);
        const int xc0 = min(max(x0, 0), WI-1);
        const int xc1 = min(max(x1, 0), WI-1);
        const int yc0 = min(max(y0, 0), HI-1);
        const int yc1 = min(max(y1, 0), HI-1);
        const float* p00 = img + (size_t)(yc0*WI + xc0)*3;
        const float* p01 = img + (size_t)(yc0*WI + xc1)*3;
        const float* p10 = img + (size_t)(yc1*WI + xc0)*3;
        const float* p11 = img + (size_t)(yc1*WI + xc1)*3;
        const float m00 = (vy0 && vx0) ? 1.f : 0.f;
        const float m01 = (vy0 && vx1) ? 1.f : 0.f;
        const float m10 = (vy1 && vx0) ? 1.f : 0.f;
        const float m11 = (vy1 && vx1) ? 1.f : 0.f;

#pragma unroll
        for (int c = 0; c < 3; ++c) {
            const float v00 = m00 * p00[c];
            const float v01 = m01 * p01[c];
            const float v10 = m10 * p10[c];
            const float v11 = m11 * p11[c];
            const float top = v00 * (1.f - dx) + v01 * dx;
            const float bot = v10 * (1.f - dx) + v11 * dx;
            o[p*3 + c] = top * (1.f - dy) + bot * dy;
        }
    }

    float* op = out + ((size_t)b*NPIX + pix0) * 3;
    *(float4*)(op + 0) = (float4){o[0], o[1], o[2],  o[3]};
    *(float4*)(op + 4) = (float4){o[4], o[5], o[6],  o[7]};
    *(float4*)(op + 8) = (float4){o[8], o[9], o[10], o[11]};
}

// ---------------------------------------------------------------------------
extern "C" void kernel_launch(void* const* d_in, const int* in_sizes, int n_in,
                              void* d_out, int out_size, void* d_ws, size_t ws_size,
                              hipStream_t stream) {
    const float* x   = (const float*)d_in[0];
    const float* w1  = (const float*)d_in[1];
    const float* b1  = (const float*)d_in[2];
    const float* w2  = (const float*)d_in[3];
    const float* b2  = (const float*)d_in[4];
    const float* fw  = (const float*)d_in[5];
    const float* fb  = (const float*)d_in[6];
    float* out = (float*)d_out;

    char* ws = (char*)d_ws;
    f16*  p1      = (f16*)ws;                                // 12,166,144 B
    float* p2     = (float*)(ws + 12166144);                 //  6,922,240 B
    float* partial= (float*)(ws + 19088384);                 //     24,576 B
    float* th     = (float*)(ws + 19113216);                 //      1,536 B

    conv1_kernel<<<dim3(NROWG, BATCH), 256, 0, stream>>>(x, w1, b1, p1);
    conv2_kernel<<<dim3(P2H, BATCH), 256, 0, stream>>>(p1, w2, b2, p2);
    fcA_kernel<<<dim3(FCSL, BATCH), 256, 0, stream>>>(p2, fw, partial);
    fcB_kernel<<<dim3(1), 384, 0, stream>>>(partial, fb, th);

    resample_kernel<<<dim3(BATCH*49), 256, 0, stream>>>(x, th, out);
}

// Round 11
// 71.627 us; speedup vs baseline: 1.2219x; 1.2219x over previous
//
#include <hip/hip_runtime.h>
#include <math.h>

#define BATCH 64
#define HI 224
#define WI 224
#define P1H 109
#define P1W 109
#define P2H 52
#define P2W 52
#define NPIX (HI*WI)                  // 50176 = 196 * 256

typedef _Float16 f16;
typedef _Float16 f16x4 __attribute__((ext_vector_type(4)));
typedef _Float16 f16x8 __attribute__((ext_vector_type(8)));
typedef float    f32x4 __attribute__((ext_vector_type(4)));

#define MFMA16F(a,b,c) __builtin_amdgcn_mfma_f32_16x16x32_f16((a),(b),(c),0,0,0)

// ---------------------------------------------------------------------------
// conv1 7x7x3->8 + bias + relu + maxpool2.  MFMA 16x16x32 f16 (fp32 acc).
// kh-PAIR PACKING: B variant v = [w(kh=v) on n<8 | w(kh=v-1) on n>=8]; one
// MFMA from A-row ir accumulates conv row ir-v (n<8) and ir-v+1 (n>=8);
// vertical maxpool = shfl_xor(8)+max.  (R8 structure — measured best.)
#define PROWS 4
#define NROWG 28                      // ceil(109/4)
#define SROWS 14
#define ROWSH 896                     // f16 per staged row (224 cols * 4)
#define STOT  (SROWS*ROWSH)           // 12544
#define SPAD  12576                   // +32 zero elems for tile-13 overrun
#define NBVAR 8
__global__ __launch_bounds__(256) void conv1_kernel(
    const float* __restrict__ x, const float* __restrict__ w1,
    const float* __restrict__ b1,
    f16* __restrict__ p1)
{
    __shared__ f16 smem[SPAD + NBVAR*16*32];   // 33344 B
    f16* sh_a = smem;
    f16* sh_b = smem + SPAD;                   // [8 variant][16 n][32 k]

    const int tid  = threadIdx.x;
    const int lane = tid & 63;
    const int wave = tid >> 6;
    const int bph  = blockIdx.x;
    const int b    = blockIdx.y;
    const int ph0  = PROWS*bph;
    const int ir0  = 2*ph0;

    for (int i = tid; i < NBVAR*16*32; i += 256) sh_b[i] = (f16)0.f;
    __syncthreads();

    for (int i = tid; i < 1176; i += 256) {
        const float v = w1[i];
        const int co = i & 7;
        const int t3 = i >> 3;
        const int ci = t3 % 3;
        const int kk = t3 / 3;
        const int kh = kk / 7;
        const int kw = kk - kh*7;
        const f16 val = (f16)v;
        sh_b[(kh*16     + co  )*32 + kw*4 + ci] = val;
        sh_b[((kh+1)*16 + co+8)*32 + kw*4 + ci] = val;
    }

    for (int u = wave; u < 25; u += 4) {
        const int q = u*512 + lane*8;
        if (q >= SPAD) continue;
        const int row  = q / ROWSH;
        const int rem  = q - row*ROWSH;
        const int col0 = rem >> 2;
        const int ira  = ir0 + row;
        float f0=0.f,f1=0.f,f2=0.f,f3=0.f,f4=0.f,f5=0.f;
        if (q < STOT && ira < HI) {
            const float* src = x + ((size_t)(b*HI + ira)*WI + col0)*3;
            const float2 a = *(const float2*)(src);
            const float2 c = *(const float2*)(src+2);
            const float2 e = *(const float2*)(src+4);
            f0=a.x; f1=a.y; f2=c.x; f3=c.y; f4=e.x; f5=e.y;
        }
        f16x8 hv;
        hv[0]=(f16)f0; hv[1]=(f16)f1; hv[2]=(f16)f2; hv[3]=(f16)0.f;
        hv[4]=(f16)f3; hv[5]=(f16)f4; hv[6]=(f16)f5; hv[7]=(f16)0.f;
        *(f16x8*)(sh_a + q) = hv;
    }
    __syncthreads();

    const int n16 = lane & 15;
    const int g   = lane >> 4;

    f16x8 bv[NBVAR];
#pragma unroll
    for (int v = 0; v < NBVAR; ++v)
        bv[v] = *(const f16x8*)(sh_b + (v*16 + n16)*32 + g*8);
    const float bias = b1[n16 & 7];

    for (int t = wave; t < 14; t += 4) {
        const int abase = (t*16 + n16)*4 + g*8;
        f32x4 acc[4];
#pragma unroll
        for (int q = 0; q < 4; ++q) acc[q] = (f32x4){0.f,0.f,0.f,0.f};

#pragma unroll
        for (int ir = 0; ir < SROWS; ++ir) {
            const int sb = ir*ROWSH + abase;
            const f16x4 h0 = *(const f16x4*)(sh_a + sb);
            const f16x4 h1 = *(const f16x4*)(sh_a + sb + 4);
            const f16x8 ah = __builtin_shufflevector(h0,h1,0,1,2,3,4,5,6,7);
#pragma unroll
            for (int q = 0; q < 4; ++q) {
                const int v = ir - 2*q;
                if (v >= 0 && v < NBVAR)
                    acc[q] = MFMA16F(ah, bv[v], acc[q]);
            }
        }

#pragma unroll
        for (int pr = 0; pr < PROWS; ++pr) {
            const float h0 = fmaxf(acc[pr][0], acc[pr][1]);
            const float h1 = fmaxf(acc[pr][2], acc[pr][3]);
            const float v0 = fmaxf(h0, __shfl_xor(h0, 8));
            const float v1 = fmaxf(h1, __shfl_xor(h1, 8));
            const int ph = ph0 + pr;
            if (n16 < 8 && ph < P1H) {
                const int pc0 = t*8 + 2*g;
                const size_t rbase = ((size_t)(b*P1H + ph))*P1W*8;
                if (pc0 < P1W)
                    p1[rbase + (size_t)pc0*8 + n16] = (f16)fmaxf(v0 + bias, 0.f);
                if (pc0+1 < P1W)
                    p1[rbase + (size_t)(pc0+1)*8 + n16] = (f16)fmaxf(v1 + bias, 0.f);
            }
        }
    }
}

// ---------------------------------------------------------------------------
// conv2 5x5x8->10 + bias + relu + maxpool2, MFMA f16 single-pass. (R8)
#define C2A 6144
__global__ __launch_bounds__(256) void conv2_kernel(
    const f16* __restrict__ p1,
    const float* __restrict__ w2, const float* __restrict__ b2,
    float* __restrict__ p2)
{
    __shared__ f16 smem[C2A + 16*224];       // 19456 B
    f16* sh_a = smem;
    f16* sh_b = smem + C2A;

    const int tid = threadIdx.x;
    const int ph  = blockIdx.x;
    const int b   = blockIdx.y;

    for (int i = tid; i < 16*224; i += 256) sh_b[i] = (f16)0.f;
    for (int i = tid; i < C2A - 5232; i += 256) sh_a[5232 + i] = (f16)0.f;
    __syncthreads();

    for (int i = tid; i < 2000; i += 256) {
        const float v = w2[i];
        const int kh = i / 400;
        int rem = i - kh*400;
        const int kw = rem / 80;
        rem -= kw*80;
        const int ci = rem / 10;
        const int co = rem - ci*10;
        sh_b[co*224 + kh*40 + kw*8 + ci] = (f16)v;
    }

    const size_t gbase = ((size_t)b*P1H + 2*ph) * (P1W*8);
    const ulong2* gsrc = (const ulong2*)(p1 + gbase);
    ulong2* gdst = (ulong2*)sh_a;
    for (int c = tid; c < 654; c += 256) gdst[c] = gsrc[c];
    __syncthreads();

    const int lane = tid & 63;
    const int wave = tid >> 6;
    const int n16  = lane & 15;
    const int g    = lane >> 4;

    f16x8 bh[7];
#pragma unroll
    for (int j = 0; j < 7; ++j)
        bh[j] = *(const f16x8*)(sh_b + n16*224 + j*32 + g*8);
    const float bias = (n16 < 10) ? b2[n16] : 0.f;

    int koff[7];
#pragma unroll
    for (int j = 0; j < 7; ++j) {
        const int chunk = 4*j + g;
        const int kh = chunk / 5;
        const int kw = chunk - kh*5;
        koff[j] = kh*872 + kw*8;
    }

    for (int t = wave; t < 7; t += 4) {
        const int c0 = t*16;
        const int pbase = (c0 + n16)*8;
        float res[2][4];
#pragma unroll
        for (int ro = 0; ro < 2; ++ro) {
            f32x4 accA = {0.f,0.f,0.f,0.f};
            f32x4 accB = {0.f,0.f,0.f,0.f};
            const int rb = ro*872 + pbase;
#pragma unroll
            for (int j = 0; j < 7; ++j) {
                const int si = rb + koff[j];
                const f16x8 ah = *(const f16x8*)(sh_a + si);
                if (j & 1) accB = MFMA16F(ah, bh[j], accB);
                else       accA = MFMA16F(ah, bh[j], accA);
            }
#pragma unroll
            for (int r = 0; r < 4; ++r) res[ro][r] = accA[r] + accB[r];
        }
        if (n16 < 10) {
#pragma unroll
            for (int q = 0; q < 2; ++q) {
                const int pc = (c0 >> 1) + 2*g + q;
                if (pc < P2W) {
                    float m = fmaxf(fmaxf(res[0][2*q], res[0][2*q+1]),
                                    fmaxf(res[1][2*q], res[1][2*q+1]));
                    p2[((size_t)((b*P2H + ph)*P2W) + pc)*10 + n16] = fmaxf(m + bias, 0.f);
                }
            }
        }
    }
}

// ---------------------------------------------------------------------------
// FC stage A: partial[b][s][6], 16 K-slices of 1690 -> 1024 blocks. (R8)
#define FCSL 16
#define FCCH 1690
__global__ __launch_bounds__(256) void fcA_kernel(
    const float* __restrict__ p2, const float* __restrict__ fw,
    float* __restrict__ partial)
{
    const int s = blockIdx.x;
    const int b = blockIdx.y;
    const int base = s * FCCH;
    const float* f = p2 + (size_t)b*27040;
    float acc[6] = {0.f,0.f,0.f,0.f,0.f,0.f};
    for (int i = threadIdx.x; i < FCCH; i += 256) {
        const float v = f[base + i];
        const float* wp = fw + (size_t)(base + i)*6;
#pragma unroll
        for (int k = 0; k < 6; ++k) acc[k] = fmaf(v, wp[k], acc[k]);
    }
    __shared__ float red[4][6];
#pragma unroll
    for (int k = 0; k < 6; ++k) {
        float v = acc[k];
        for (int off = 32; off > 0; off >>= 1) v += __shfl_down(v, off);
        if ((threadIdx.x & 63) == 0) red[threadIdx.x >> 6][k] = v;
    }
    __syncthreads();
    if (threadIdx.x < 6) {
        const int k = threadIdx.x;
        partial[(b*FCSL + s)*6 + k] = red[0][k] + red[1][k] + red[2][k] + red[3][k];
    }
}

// ---------------------------------------------------------------------------
// resample (R8 1px/thread) + fcB folded in: each block serves ONE image
// (196 blocks/image, NPIX = 196*256 exactly); 6 lanes sum the 16 fcA
// partials + fb into LDS theta (same order as the old fcB -> bit-identical).
__global__ __launch_bounds__(256) void resample_kernel(
    const float* __restrict__ x, const float* __restrict__ partial,
    const float* __restrict__ fb, float* __restrict__ out)
{
    __shared__ float sth[6];
    const int tid = threadIdx.x;
    const int u   = blockIdx.x;               // 0 .. 64*196-1
    const int b   = u / 196;
    const int pix = (u - b*196) * 256 + tid;  // always < NPIX

    if (tid < 6) {
        const float* pb = partial + (size_t)b * (FCSL*6);
        float s = fb[tid];
#pragma unroll
        for (int j = 0; j < FCSL; ++j) s += pb[j*6 + tid];
        sth[tid] = s;
    }
    __syncthreads();

    const float a0 = sth[0], a1 = sth[1], a2 = sth[2];
    const float a3 = sth[3], a4 = sth[4], a5 = sth[5];

    const int yo = pix / WI;
    const int xo = pix - yo * WI;

    const float fx = (float)xo, fy = (float)yo;
    const float xq = a0*fx + a1*fy + a2;
    const float yq = a3*fx + a4*fy + a5;
    const float x0f = floorf(xq), y0f = floorf(yq);
    const float dx = xq - x0f, dy = yq - y0f;
    const int x0 = (int)x0f, y0 = (int)y0f;

    const float* img = x + (size_t)b * (NPIX*3);

    const int x1 = x0 + 1, y1 = y0 + 1;
    const bool vx0 = (x0 >= 0) && (x0 <= WI-1);
    const bool vx1 = (x1 >= 0) && (x1 <= WI-1);
    const bool vy0 = (y0 >= 0) && (y0 <= HI-1);
    const bool vy1 = (y1 >= 0) && (y1 <= HI-1);
    const int xc0 = min(max(x0, 0), WI-1);
    const int xc1 = min(max(x1, 0), WI-1);
    const int yc0 = min(max(y0, 0), HI-1);
    const int yc1 = min(max(y1, 0), HI-1);
    const float* p00 = img + (size_t)(yc0*WI + xc0)*3;
    const float* p01 = img + (size_t)(yc0*WI + xc1)*3;
    const float* p10 = img + (size_t)(yc1*WI + xc0)*3;
    const float* p11 = img + (size_t)(yc1*WI + xc1)*3;
    const float m00 = (vy0 && vx0) ? 1.f : 0.f;
    const float m01 = (vy0 && vx1) ? 1.f : 0.f;
    const float m10 = (vy1 && vx0) ? 1.f : 0.f;
    const float m11 = (vy1 && vx1) ? 1.f : 0.f;

    float* op = out + ((size_t)b*NPIX + pix) * 3;
#pragma unroll
    for (int c = 0; c < 3; ++c) {
        const float v00 = m00 * p00[c];
        const float v01 = m01 * p01[c];
        const float v10 = m10 * p10[c];
        const float v11 = m11 * p11[c];
        const float top = v00 * (1.f - dx) + v01 * dx;
        const float bot = v10 * (1.f - dx) + v11 * dx;
        op[c] = top * (1.f - dy) + bot * dy;
    }
}

// ---------------------------------------------------------------------------
extern "C" void kernel_launch(void* const* d_in, const int* in_sizes, int n_in,
                              void* d_out, int out_size, void* d_ws, size_t ws_size,
                              hipStream_t stream) {
    const float* x   = (const float*)d_in[0];
    const float* w1  = (const float*)d_in[1];
    const float* b1  = (const float*)d_in[2];
    const float* w2  = (const float*)d_in[3];
    const float* b2  = (const float*)d_in[4];
    const float* fw  = (const float*)d_in[5];
    const float* fb  = (const float*)d_in[6];
    float* out = (float*)d_out;

    char* ws = (char*)d_ws;
    f16*  p1      = (f16*)ws;                                // 12,166,144 B
    float* p2     = (float*)(ws + 12166144);                 //  6,922,240 B
    float* partial= (float*)(ws + 19088384);                 //     24,576 B

    conv1_kernel<<<dim3(NROWG, BATCH), 256, 0, stream>>>(x, w1, b1, p1);
    conv2_kernel<<<dim3(P2H, BATCH), 256, 0, stream>>>(p1, w2, b2, p2);
    fcA_kernel<<<dim3(FCSL, BATCH), 256, 0, stream>>>(p2, fw, partial);
    resample_kernel<<<dim3(BATCH*196), 256, 0, stream>>>(x, partial, fb, out);
}